// Round 11
// baseline (111.901 us; speedup 1.0000x reference)
//
#include <hip/hip_runtime.h>
#include <hip/hip_fp16.h>

#define KNB 31
#define CH 64
#define TEMP_INV 10.0f   // 1 / temperature(0.1)

typedef _Float16 h2 __attribute__((ext_vector_type(2)));
typedef float f2 __attribute__((ext_vector_type(2)));

// ---------------------------------------------------------------------------
// ws layout:
//   bytes [0, 16)    : double ws[2]  (sum(loss*mask), sum(mask))
//   bytes [16, 20)   : unsigned done-counter (last-block finalize)
//   bytes [256, ...) : fp8 feature table (N*64 B) | fp16 table (N*128 B)
// ---------------------------------------------------------------------------

__global__ void ch_init_ws(double* __restrict__ ws, unsigned* __restrict__ ctr) {
    ws[0] = 0.0;
    ws[1] = 0.0;
    *ctr  = 0u;
}

// features f32 -> fp8 e4m3 table (8 floats -> 8 bytes per thread); zeroes ws.
__global__ __launch_bounds__(256) void ch_cvt8(
    const float* __restrict__ in, unsigned char* __restrict__ out,
    double* __restrict__ ws, unsigned* __restrict__ ctr, int total8)
{
    const int idx = blockIdx.x * blockDim.x + threadIdx.x;
    if (idx == 0) { ws[0] = 0.0; ws[1] = 0.0; *ctr = 0u; }
    if (idx >= total8) return;
    const float4* ip = reinterpret_cast<const float4*>(in) + (size_t)idx * 2;
    const float4 a = ip[0];
    const float4 b = ip[1];
    unsigned lo = 0u, hi = 0u;
    lo = __builtin_amdgcn_cvt_pk_fp8_f32(a.x, a.y, lo, false);
    lo = __builtin_amdgcn_cvt_pk_fp8_f32(a.z, a.w, lo, true);
    hi = __builtin_amdgcn_cvt_pk_fp8_f32(b.x, b.y, hi, false);
    hi = __builtin_amdgcn_cvt_pk_fp8_f32(b.z, b.w, hi, true);
    uint2 o; o.x = lo; o.y = hi;
    reinterpret_cast<uint2*>(out)[idx] = o;
}

__device__ __forceinline__ void fp8_to_f32x16(const uint4 u, float* f) {
    union { uint4 v; unsigned w[4]; } U;
    U.v = u;
    #pragma unroll
    for (int q = 0; q < 4; ++q) {
        const f2 p0 = __builtin_amdgcn_cvt_pk_f32_fp8(U.w[q], false);
        const f2 p1 = __builtin_amdgcn_cvt_pk_f32_fp8(U.w[q], true);
        f[4 * q + 0] = p0[0]; f[4 * q + 1] = p0[1];
        f[4 * q + 2] = p1[0]; f[4 * q + 3] = p1[1];
    }
}

// decode-and-accumulate: no 16-float temp array
__device__ __forceinline__ float fp8_sub_sq_acc(const float* fA, const uint4 bu, float s) {
    union { uint4 v; unsigned w[4]; } U;
    U.v = bu;
    #pragma unroll
    for (int q = 0; q < 4; ++q) {
        const f2 p0 = __builtin_amdgcn_cvt_pk_f32_fp8(U.w[q], false);
        const f2 p1 = __builtin_amdgcn_cvt_pk_f32_fp8(U.w[q], true);
        float d;
        d = fA[4 * q + 0] - p0[0]; s = fmaf(d, d, s);
        d = fA[4 * q + 1] - p0[1]; s = fmaf(d, d, s);
        d = fA[4 * q + 2] - p1[0]; s = fmaf(d, d, s);
        d = fA[4 * q + 3] - p1[1]; s = fmaf(d, d, s);
    }
    return s;
}

// fp8 main: 4 lanes/point, ONE point per quad, TWO neighbor chains per lane
// (j in [0,16) and [16,31)) sharing the same fA registers. Doubles outstanding
// gather requests per lane at unchanged (8 waves/EU) occupancy — R10 lesson:
// ILP must be grown, not traded against waves. ~55 VGPR working set.
__global__ __launch_bounds__(256) void ch_main8d(
    const unsigned char* __restrict__ tab8,   // (N, 64) fp8 e4m3
    const int*           __restrict__ labels, // (N,)
    const int*           __restrict__ nidx,   // (N, 31)
    double*              __restrict__ ws,
    unsigned*            __restrict__ ctr,
    float*               __restrict__ out,
    int n)
{
    const int t   = threadIdx.x;
    const int i   = blockIdx.x * (256 / 4) + (t >> 2);
    const int sub = t & 3;

    float loss_w = 0.0f;
    float pm_f   = 0.0f;

    if (i < n) {
        // own row fragment (shared by both chains)
        float fA[16];
        fp8_to_f32x16(reinterpret_cast<const uint4*>(tab8 + (size_t)i * CH)[sub], fA);

        const int lab   = labels[i];
        const int* nrow = nidx + (size_t)i * KNB;

        float m0 = -1e30f, se0 = 0.0f, sp0 = 0.0f;   // chain 0: j = 0..15
        float m1 = -1e30f, se1 = 0.0f, sp1 = 0.0f;   // chain 1: j = 16..30
        unsigned pmask = 0u;                          // 31-bit posmask

        #pragma unroll 2
        for (int j = 0; j < 16; ++j) {
            const bool c1  = (j < 15);                // chain1 valid (j+16 <= 30)
            const int  nj0 = nrow[j];
            const int  nj1 = nrow[c1 ? (j + 16) : 30];

            const uint4 b0 = reinterpret_cast<const uint4*>(tab8 + (size_t)nj0 * CH)[sub];
            const uint4 b1 = reinterpret_cast<const uint4*>(tab8 + (size_t)nj1 * CH)[sub];

            float s0 = fp8_sub_sq_acc(fA, b0, 0.0f);
            float s1 = fp8_sub_sq_acc(fA, b1, 0.0f);

            s0 += __shfl_xor(s0, 1);
            s0 += __shfl_xor(s0, 2);
            s1 += __shfl_xor(s1, 1);
            s1 += __shfl_xor(s1, 2);

            const float l0 = -(sqrtf(s0) + 1e-8f);
            const float l1 = -(sqrtf(s1) + 1e-8f);

            const bool pm0 = (labels[nj0] == lab);
            pmask |= pm0 ? (1u << j) : 0u;

            if (l0 > m0) {
                const float r = __expf((m0 - l0) * TEMP_INV);
                se0 *= r; sp0 *= r; m0 = l0;
            }
            const float e0 = __expf((l0 - m0) * TEMP_INV);
            se0 += e0;
            if (pm0) sp0 += e0;

            if (c1) {                                  // uniform branch
                const bool pm1 = (labels[nj1] == lab);
                pmask |= pm1 ? (1u << (j + 16)) : 0u;

                if (l1 > m1) {
                    const float r = __expf((m1 - l1) * TEMP_INV);
                    se1 *= r; sp1 *= r; m1 = l1;
                }
                const float e1 = __expf((l1 - m1) * TEMP_INV);
                se1 += e1;
                if (pm1) sp1 += e1;
            }
        }

        // exact online-softmax merge of the two chains
        const float mm = fmaxf(m0, m1);
        const float r0 = __expf((m0 - mm) * TEMP_INV);
        const float r1 = __expf((m1 - mm) * TEMP_INV);
        const float se = se0 * r0 + se1 * r1;
        const float sp = sp0 * r0 + sp1 * r1;

        const int cnt = __popc(pmask);
        if (sub == 0 && cnt > 0 && cnt < KNB) {
            loss_w = -logf(sp / se + 1e-8f);
            pm_f   = 1.0f;
        }
    }

    // ---- block reduction, one double atomic per block; last block writes out
    __shared__ float s_l[256];
    __shared__ float s_c[256];
    s_l[t] = loss_w;
    s_c[t] = pm_f;
    __syncthreads();
    #pragma unroll
    for (int off = 128; off > 0; off >>= 1) {
        if (t < off) {
            s_l[t] += s_l[t + off];
            s_c[t] += s_c[t + off];
        }
        __syncthreads();
    }
    if (t == 0) {
        atomicAdd(ws,     (double)s_l[0]);
        atomicAdd(ws + 1, (double)s_c[0]);
        __threadfence();
        const unsigned old = atomicAdd(ctr, 1u);
        if (old == gridDim.x - 1) {
            const double sl = atomicAdd(ws, 0.0);
            const double sc = atomicAdd(ws + 1, 0.0);
            const double c  = (sc < 1.0) ? 1.0 : sc;
            out[0] = (float)(sl / c);   // WEIGHT = 1.0
        }
    }
}

// ---------------------------------------------------------------------------
// Fallback path (R2-exact, proven): fp16 table / f32 direct + separate finalize
// ---------------------------------------------------------------------------
__global__ __launch_bounds__(256) void ch_cvt(
    const float* __restrict__ in, __half* __restrict__ out, int total8)
{
    const int idx = blockIdx.x * blockDim.x + threadIdx.x;
    if (idx >= total8) return;
    const float4* ip = reinterpret_cast<const float4*>(in) + (size_t)idx * 2;
    const float4 a = ip[0];
    const float4 b = ip[1];
    union { uint4 u; __half2 h[4]; } o;
    o.h[0] = __floats2half2_rn(a.x, a.y);
    o.h[1] = __floats2half2_rn(a.z, a.w);
    o.h[2] = __floats2half2_rn(b.x, b.y);
    o.h[3] = __floats2half2_rn(b.z, b.w);
    reinterpret_cast<uint4*>(out)[idx] = o.u;
}

__device__ __forceinline__ float dot2acc(h2 d, float s) {
    return __builtin_amdgcn_fdot2(d, d, s, false);
}

template <bool FP16>
__global__ __launch_bounds__(256) void ch_main4(
    const float*  __restrict__ feat,
    const __half* __restrict__ tab,
    const int*    __restrict__ labels,
    const int*    __restrict__ nidx,
    double*       __restrict__ ws,
    int n)
{
    const int t   = threadIdx.x;
    const int i   = blockIdx.x * (256 / 4) + (t >> 2);
    const int sub = t & 3;

    float loss_w = 0.0f;
    float pm_f   = 0.0f;

    if (i < n) {
        float f[16];
        union { uint4 u[2]; h2 h[8]; } A;
        if constexpr (FP16) {
            const uint4* ap = reinterpret_cast<const uint4*>(tab + (size_t)i * CH + sub * 16);
            A.u[0] = ap[0];
            A.u[1] = ap[1];
        } else {
            const float4* ap = reinterpret_cast<const float4*>(feat + (size_t)i * CH + sub * 16);
            #pragma unroll
            for (int q = 0; q < 4; ++q) {
                const float4 v = ap[q];
                f[4 * q]     = v.x;
                f[4 * q + 1] = v.y;
                f[4 * q + 2] = v.z;
                f[4 * q + 3] = v.w;
            }
        }

        const int lab = labels[i];
        float m = -1e30f, se = 0.0f, sp = 0.0f;
        int cnt = 0;

        #pragma unroll 2
        for (int j = 0; j < KNB; ++j) {
            const int nj = nidx[(size_t)i * KNB + j];

            float s = 0.0f;
            if constexpr (FP16) {
                union { uint4 u[2]; h2 h[8]; } B;
                const uint4* bp = reinterpret_cast<const uint4*>(tab + (size_t)nj * CH + sub * 16);
                B.u[0] = bp[0];
                B.u[1] = bp[1];
                #pragma unroll
                for (int q = 0; q < 8; ++q) {
                    const h2 d = A.h[q] - B.h[q];
                    s = dot2acc(d, s);
                }
            } else {
                const float4* bp = reinterpret_cast<const float4*>(feat + (size_t)nj * CH + sub * 16);
                #pragma unroll
                for (int q = 0; q < 4; ++q) {
                    const float4 v = bp[q];
                    const float dx = f[4 * q]     - v.x;
                    const float dy = f[4 * q + 1] - v.y;
                    const float dz = f[4 * q + 2] - v.z;
                    const float dw = f[4 * q + 3] - v.w;
                    s += dx * dx + dy * dy + dz * dz + dw * dw;
                }
            }
            s += __shfl_xor(s, 1);
            s += __shfl_xor(s, 2);

            const float l = -(sqrtf(s) + 1e-8f);
            const bool pm = (labels[nj] == lab);
            cnt += pm ? 1 : 0;

            if (l > m) {
                const float r = __expf((m - l) * TEMP_INV);
                se *= r; sp *= r; m = l;
            }
            const float e = __expf((l - m) * TEMP_INV);
            se += e;
            if (pm) sp += e;
        }

        if (sub == 0 && cnt > 0 && cnt < KNB) {
            loss_w = -logf(sp / se + 1e-8f);
            pm_f   = 1.0f;
        }
    }

    __shared__ float s_l[256];
    __shared__ float s_c[256];
    s_l[t] = loss_w;
    s_c[t] = pm_f;
    __syncthreads();
    #pragma unroll
    for (int off = 128; off > 0; off >>= 1) {
        if (t < off) {
            s_l[t] += s_l[t + off];
            s_c[t] += s_c[t + off];
        }
        __syncthreads();
    }
    if (t == 0) {
        atomicAdd(ws,     (double)s_l[0]);
        atomicAdd(ws + 1, (double)s_c[0]);
    }
}

__global__ void ch_finalize(const double* __restrict__ ws, float* __restrict__ out) {
    double c = ws[1];
    if (c < 1.0) c = 1.0;
    out[0] = (float)(ws[0] / c);   // WEIGHT = 1.0
}

extern "C" void kernel_launch(void* const* d_in, const int* in_sizes, int n_in,
                              void* d_out, int out_size, void* d_ws, size_t ws_size,
                              hipStream_t stream) {
    const float* feat   = (const float*)d_in[0];
    const int*   labels = (const int*)d_in[1];
    const int*   nidx   = (const int*)d_in[2];
    float*       out    = (float*)d_out;
    double*      ws     = (double*)d_ws;
    unsigned*    ctr    = (unsigned*)((char*)d_ws + 16);

    const int n = in_sizes[1];                 // N = 100000
    const int total8 = n * CH / 8;

    if (ws_size >= 256 + (size_t)n * CH) {              // fp8 table: N*64 B
        unsigned char* tab = (unsigned char*)d_ws + 256;
        ch_cvt8<<<(total8 + 255) / 256, 256, 0, stream>>>(feat, tab, ws, ctr, total8);
        const int blocks = (n + 63) / 64;               // 64 points per block
        ch_main8d<<<blocks, 256, 0, stream>>>(tab, labels, nidx, ws, ctr, out, n);
        return;
    }

    ch_init_ws<<<1, 1, 0, stream>>>(ws, ctr);
    const int blocks = (n + 63) / 64;
    if (ws_size >= 256 + (size_t)n * CH * 2) {          // fp16 table
        __half* tab = reinterpret_cast<__half*>((char*)d_ws + 256);
        ch_cvt<<<(total8 + 255) / 256, 256, 0, stream>>>(feat, tab, total8);
        ch_main4<true><<<blocks, 256, 0, stream>>>(feat, tab, labels, nidx, ws, n);
    } else {                                            // f32 direct
        ch_main4<false><<<blocks, 256, 0, stream>>>(feat, nullptr, labels, nidx, ws, n);
    }
    ch_finalize<<<1, 1, 0, stream>>>(ws, out);
}

// Round 12
// 109.666 us; speedup vs baseline: 1.0204x; 1.0204x over previous
//
#include <hip/hip_runtime.h>
#include <hip/hip_fp16.h>

#define KNB 31
#define CH 64
#define TEMP_INV 10.0f   // 1 / temperature(0.1)

typedef _Float16 h2 __attribute__((ext_vector_type(2)));
typedef float f2 __attribute__((ext_vector_type(2)));

// ---------------------------------------------------------------------------
// ws layout:
//   bytes [0, 16)    : double ws[2]  (sum(loss*mask), sum(mask))
//   bytes [16, 20)   : unsigned done-counter (last-block finalize)
//   bytes [256, ...) : fp8 feature table (N*64 B) | fp16 table (N*128 B)
// ---------------------------------------------------------------------------

__global__ void ch_init_ws(double* __restrict__ ws, unsigned* __restrict__ ctr) {
    ws[0] = 0.0;
    ws[1] = 0.0;
    *ctr  = 0u;
}

// features f32 -> fp8 e4m3 table (8 floats -> 8 bytes per thread); zeroes ws.
__global__ __launch_bounds__(256) void ch_cvt8(
    const float* __restrict__ in, unsigned char* __restrict__ out,
    double* __restrict__ ws, unsigned* __restrict__ ctr, int total8)
{
    const int idx = blockIdx.x * blockDim.x + threadIdx.x;
    if (idx == 0) { ws[0] = 0.0; ws[1] = 0.0; *ctr = 0u; }
    if (idx >= total8) return;
    const float4* ip = reinterpret_cast<const float4*>(in) + (size_t)idx * 2;
    const float4 a = ip[0];
    const float4 b = ip[1];
    unsigned lo = 0u, hi = 0u;
    lo = __builtin_amdgcn_cvt_pk_fp8_f32(a.x, a.y, lo, false);
    lo = __builtin_amdgcn_cvt_pk_fp8_f32(a.z, a.w, lo, true);
    hi = __builtin_amdgcn_cvt_pk_fp8_f32(b.x, b.y, hi, false);
    hi = __builtin_amdgcn_cvt_pk_fp8_f32(b.z, b.w, hi, true);
    uint2 o; o.x = lo; o.y = hi;
    reinterpret_cast<uint2*>(out)[idx] = o;
}

// 16-channel fp8 block distance: decode A-word and B-word pairs, fma-accumulate.
__device__ __forceinline__ float fp8_blk16_acc(const uint4 au, const uint4 bu, float s) {
    union { uint4 v; unsigned w[4]; } A, B;
    A.v = au;
    B.v = bu;
    #pragma unroll
    for (int q = 0; q < 4; ++q) {
        const f2 a0 = __builtin_amdgcn_cvt_pk_f32_fp8(A.w[q], false);
        const f2 a1 = __builtin_amdgcn_cvt_pk_f32_fp8(A.w[q], true);
        const f2 b0 = __builtin_amdgcn_cvt_pk_f32_fp8(B.w[q], false);
        const f2 b1 = __builtin_amdgcn_cvt_pk_f32_fp8(B.w[q], true);
        float d;
        d = a0[0] - b0[0]; s = fmaf(d, d, s);
        d = a0[1] - b0[1]; s = fmaf(d, d, s);
        d = a1[0] - b1[0]; s = fmaf(d, d, s);
        d = a1[1] - b1[1]; s = fmaf(d, d, s);
    }
    return s;
}

// Row-per-lane fp8 main: 4 lanes/point; lane sub owns neighbors j = 4g+sub and
// loads each FULL 64 B row as 4 independent dwordx4 -> 4+ outstanding requests
// per lane, ZERO shuffles inside the j-loop. Per-lane online-softmax chains,
// merged once at the end (R11-validated merge). ~55 VGPR, no spill at the
// default 64-reg/8-wave target. Last block finalizes out[0].
__global__ __launch_bounds__(256) void ch_main_rpl(
    const unsigned char* __restrict__ tab8,   // (N, 64) fp8 e4m3
    const int*           __restrict__ labels, // (N,)
    const int*           __restrict__ nidx,   // (N, 31)
    double*              __restrict__ ws,
    unsigned*            __restrict__ ctr,
    float*               __restrict__ out,
    int n)
{
    const int t   = threadIdx.x;
    const int i   = blockIdx.x * (256 / 4) + (t >> 2);
    const int sub = t & 3;

    float loss_w = 0.0f;
    float pm_f   = 0.0f;

    if (i < n) {
        // own full row, kept as fp8 (16 VGPR), decoded per use
        uint4 A0, A1, A2, A3;
        {
            const uint4* ar = reinterpret_cast<const uint4*>(tab8 + (size_t)i * CH);
            A0 = ar[0]; A1 = ar[1]; A2 = ar[2]; A3 = ar[3];
        }

        const int lab   = labels[i];
        const int* nrow = nidx + (size_t)i * KNB;

        float m = -1e30f, se = 0.0f, sp = 0.0f;   // this lane's chain
        unsigned pmask = 0u;

        #pragma unroll
        for (int g = 0; g < 8; ++g) {
            const int  j     = g * 4 + sub;
            const bool valid = (j < KNB);          // only g=7,sub=3 invalid
            const int  jc    = valid ? j : (KNB - 1);
            const int  nj    = nrow[jc];           // quad reads 16 contiguous B

            const uint4* br = reinterpret_cast<const uint4*>(tab8 + (size_t)nj * CH);
            const uint4 B0 = br[0];                // 4 independent 16 B loads
            const uint4 B1 = br[1];
            const uint4 B2 = br[2];
            const uint4 B3 = br[3];

            float s = 0.0f;
            s = fp8_blk16_acc(A0, B0, s);
            s = fp8_blk16_acc(A1, B1, s);
            s = fp8_blk16_acc(A2, B2, s);
            s = fp8_blk16_acc(A3, B3, s);

            const float l  = -(sqrtf(s) + 1e-8f);
            const bool  pm = valid && (labels[nj] == lab);
            pmask |= pm ? (1u << jc) : 0u;

            if (valid) {
                if (l > m) {
                    const float r = __expf((m - l) * TEMP_INV);
                    se *= r; sp *= r; m = l;
                }
                const float e = __expf((l - m) * TEMP_INV);
                se += e;
                if (pm) sp += e;
            }
        }

        // merge the 4 per-lane chains across the quad (2 butterfly stages)
        #pragma unroll
        for (int d = 1; d <= 2; d <<= 1) {
            const float    mo  = __shfl_xor(m, d);
            const float    seo = __shfl_xor(se, d);
            const float    spo = __shfl_xor(sp, d);
            const unsigned po  = (unsigned)__shfl_xor((int)pmask, d);
            const float mm = fmaxf(m, mo);
            const float r0 = __expf((m  - mm) * TEMP_INV);
            const float r1 = __expf((mo - mm) * TEMP_INV);
            se = se * r0 + seo * r1;
            sp = sp * r0 + spo * r1;
            m  = mm;
            pmask |= po;
        }

        const int cnt = __popc(pmask);
        if (sub == 0 && cnt > 0 && cnt < KNB) {
            loss_w = -logf(sp / se + 1e-8f);
            pm_f   = 1.0f;
        }
    }

    // ---- block reduction, one double atomic per block; last block writes out
    __shared__ float s_l[256];
    __shared__ float s_c[256];
    s_l[t] = loss_w;
    s_c[t] = pm_f;
    __syncthreads();
    #pragma unroll
    for (int off = 128; off > 0; off >>= 1) {
        if (t < off) {
            s_l[t] += s_l[t + off];
            s_c[t] += s_c[t + off];
        }
        __syncthreads();
    }
    if (t == 0) {
        atomicAdd(ws,     (double)s_l[0]);
        atomicAdd(ws + 1, (double)s_c[0]);
        __threadfence();
        const unsigned old = atomicAdd(ctr, 1u);
        if (old == gridDim.x - 1) {
            const double sl = atomicAdd(ws, 0.0);
            const double sc = atomicAdd(ws + 1, 0.0);
            const double c  = (sc < 1.0) ? 1.0 : sc;
            out[0] = (float)(sl / c);   // WEIGHT = 1.0
        }
    }
}

// ---------------------------------------------------------------------------
// Fallback path (R2-exact, proven): fp16 table / f32 direct + separate finalize
// ---------------------------------------------------------------------------
__global__ __launch_bounds__(256) void ch_cvt(
    const float* __restrict__ in, __half* __restrict__ out, int total8)
{
    const int idx = blockIdx.x * blockDim.x + threadIdx.x;
    if (idx >= total8) return;
    const float4* ip = reinterpret_cast<const float4*>(in) + (size_t)idx * 2;
    const float4 a = ip[0];
    const float4 b = ip[1];
    union { uint4 u; __half2 h[4]; } o;
    o.h[0] = __floats2half2_rn(a.x, a.y);
    o.h[1] = __floats2half2_rn(a.z, a.w);
    o.h[2] = __floats2half2_rn(b.x, b.y);
    o.h[3] = __floats2half2_rn(b.z, b.w);
    reinterpret_cast<uint4*>(out)[idx] = o.u;
}

__device__ __forceinline__ float dot2acc(h2 d, float s) {
    return __builtin_amdgcn_fdot2(d, d, s, false);
}

template <bool FP16>
__global__ __launch_bounds__(256) void ch_main4(
    const float*  __restrict__ feat,
    const __half* __restrict__ tab,
    const int*    __restrict__ labels,
    const int*    __restrict__ nidx,
    double*       __restrict__ ws,
    int n)
{
    const int t   = threadIdx.x;
    const int i   = blockIdx.x * (256 / 4) + (t >> 2);
    const int sub = t & 3;

    float loss_w = 0.0f;
    float pm_f   = 0.0f;

    if (i < n) {
        float f[16];
        union { uint4 u[2]; h2 h[8]; } A;
        if constexpr (FP16) {
            const uint4* ap = reinterpret_cast<const uint4*>(tab + (size_t)i * CH + sub * 16);
            A.u[0] = ap[0];
            A.u[1] = ap[1];
        } else {
            const float4* ap = reinterpret_cast<const float4*>(feat + (size_t)i * CH + sub * 16);
            #pragma unroll
            for (int q = 0; q < 4; ++q) {
                const float4 v = ap[q];
                f[4 * q]     = v.x;
                f[4 * q + 1] = v.y;
                f[4 * q + 2] = v.z;
                f[4 * q + 3] = v.w;
            }
        }

        const int lab = labels[i];
        float m = -1e30f, se = 0.0f, sp = 0.0f;
        int cnt = 0;

        #pragma unroll 2
        for (int j = 0; j < KNB; ++j) {
            const int nj = nidx[(size_t)i * KNB + j];

            float s = 0.0f;
            if constexpr (FP16) {
                union { uint4 u[2]; h2 h[8]; } B;
                const uint4* bp = reinterpret_cast<const uint4*>(tab + (size_t)nj * CH + sub * 16);
                B.u[0] = bp[0];
                B.u[1] = bp[1];
                #pragma unroll
                for (int q = 0; q < 8; ++q) {
                    const h2 d = A.h[q] - B.h[q];
                    s = dot2acc(d, s);
                }
            } else {
                const float4* bp = reinterpret_cast<const float4*>(feat + (size_t)nj * CH + sub * 16);
                #pragma unroll
                for (int q = 0; q < 4; ++q) {
                    const float4 v = bp[q];
                    const float dx = f[4 * q]     - v.x;
                    const float dy = f[4 * q + 1] - v.y;
                    const float dz = f[4 * q + 2] - v.z;
                    const float dw = f[4 * q + 3] - v.w;
                    s += dx * dx + dy * dy + dz * dz + dw * dw;
                }
            }
            s += __shfl_xor(s, 1);
            s += __shfl_xor(s, 2);

            const float l = -(sqrtf(s) + 1e-8f);
            const bool pm = (labels[nj] == lab);
            cnt += pm ? 1 : 0;

            if (l > m) {
                const float r = __expf((m - l) * TEMP_INV);
                se *= r; sp *= r; m = l;
            }
            const float e = __expf((l - m) * TEMP_INV);
            se += e;
            if (pm) sp += e;
        }

        if (sub == 0 && cnt > 0 && cnt < KNB) {
            loss_w = -logf(sp / se + 1e-8f);
            pm_f   = 1.0f;
        }
    }

    __shared__ float s_l[256];
    __shared__ float s_c[256];
    s_l[t] = loss_w;
    s_c[t] = pm_f;
    __syncthreads();
    #pragma unroll
    for (int off = 128; off > 0; off >>= 1) {
        if (t < off) {
            s_l[t] += s_l[t + off];
            s_c[t] += s_c[t + off];
        }
        __syncthreads();
    }
    if (t == 0) {
        atomicAdd(ws,     (double)s_l[0]);
        atomicAdd(ws + 1, (double)s_c[0]);
    }
}

__global__ void ch_finalize(const double* __restrict__ ws, float* __restrict__ out) {
    double c = ws[1];
    if (c < 1.0) c = 1.0;
    out[0] = (float)(ws[0] / c);   // WEIGHT = 1.0
}

extern "C" void kernel_launch(void* const* d_in, const int* in_sizes, int n_in,
                              void* d_out, int out_size, void* d_ws, size_t ws_size,
                              hipStream_t stream) {
    const float* feat   = (const float*)d_in[0];
    const int*   labels = (const int*)d_in[1];
    const int*   nidx   = (const int*)d_in[2];
    float*       out    = (float*)d_out;
    double*      ws     = (double*)d_ws;
    unsigned*    ctr    = (unsigned*)((char*)d_ws + 16);

    const int n = in_sizes[1];                 // N = 100000
    const int total8 = n * CH / 8;

    if (ws_size >= 256 + (size_t)n * CH) {              // fp8 table: N*64 B
        unsigned char* tab = (unsigned char*)d_ws + 256;
        ch_cvt8<<<(total8 + 255) / 256, 256, 0, stream>>>(feat, tab, ws, ctr, total8);
        const int blocks = (n + 63) / 64;               // 64 points per block
        ch_main_rpl<<<blocks, 256, 0, stream>>>(tab, labels, nidx, ws, ctr, out, n);
        return;
    }

    ch_init_ws<<<1, 1, 0, stream>>>(ws, ctr);
    const int blocks = (n + 63) / 64;
    if (ws_size >= 256 + (size_t)n * CH * 2) {          // fp16 table
        __half* tab = reinterpret_cast<__half*>((char*)d_ws + 256);
        ch_cvt<<<(total8 + 255) / 256, 256, 0, stream>>>(feat, tab, total8);
        ch_main4<true><<<blocks, 256, 0, stream>>>(feat, tab, labels, nidx, ws, n);
    } else {                                            // f32 direct
        ch_main4<false><<<blocks, 256, 0, stream>>>(feat, nullptr, labels, nidx, ws, n);
    }
    ch_finalize<<<1, 1, 0, stream>>>(ws, out);
}

// Round 13
// 108.759 us; speedup vs baseline: 1.0289x; 1.0083x over previous
//
#include <hip/hip_runtime.h>
#include <hip/hip_fp16.h>

#define KNB 31
#define CH 64
#define TEMP_INV 10.0f   // 1 / temperature(0.1)

typedef _Float16 h2 __attribute__((ext_vector_type(2)));
typedef float f2 __attribute__((ext_vector_type(2)));

// ---------------------------------------------------------------------------
// ws layout:
//   bytes [0, 16)    : double ws[2]  (sum(loss*mask), sum(mask))
//   bytes [16, 20)   : unsigned done-counter (last-block finalize)
//   bytes [256, ...) : fp8 feature table (N*64 B) | fp16 table (N*128 B)
// ---------------------------------------------------------------------------

__global__ void ch_init_ws(double* __restrict__ ws, unsigned* __restrict__ ctr) {
    ws[0] = 0.0;
    ws[1] = 0.0;
    *ctr  = 0u;
}

// features f32 -> fp8 e4m3 table (8 floats -> 8 bytes per thread); zeroes ws.
__global__ __launch_bounds__(256) void ch_cvt8(
    const float* __restrict__ in, unsigned char* __restrict__ out,
    double* __restrict__ ws, unsigned* __restrict__ ctr, int total8)
{
    const int idx = blockIdx.x * blockDim.x + threadIdx.x;
    if (idx == 0) { ws[0] = 0.0; ws[1] = 0.0; *ctr = 0u; }
    if (idx >= total8) return;
    const float4* ip = reinterpret_cast<const float4*>(in) + (size_t)idx * 2;
    const float4 a = ip[0];
    const float4 b = ip[1];
    unsigned lo = 0u, hi = 0u;
    lo = __builtin_amdgcn_cvt_pk_fp8_f32(a.x, a.y, lo, false);
    lo = __builtin_amdgcn_cvt_pk_fp8_f32(a.z, a.w, lo, true);
    hi = __builtin_amdgcn_cvt_pk_fp8_f32(b.x, b.y, hi, false);
    hi = __builtin_amdgcn_cvt_pk_fp8_f32(b.y, b.w, hi, true);   // placeholder overwritten below
    hi = 0u;
    hi = __builtin_amdgcn_cvt_pk_fp8_f32(b.x, b.y, hi, false);
    hi = __builtin_amdgcn_cvt_pk_fp8_f32(b.z, b.w, hi, true);
    uint2 o; o.x = lo; o.y = hi;
    reinterpret_cast<uint2*>(out)[idx] = o;
}

// fp8 main — R8-exact structure (proven 69.5 us): 4 lanes/point, lane sub owns
// 16 channels (one uint4 = 16 fp8), quad-cooperative 64 B row gathers, online
// softmax. Only delta vs R8: last-block finalize tail (proven R10-R12).
__global__ __launch_bounds__(256) void ch_main8q(
    const unsigned char* __restrict__ tab8,   // (N, 64) fp8 e4m3
    const int*           __restrict__ labels, // (N,)
    const int*           __restrict__ nidx,   // (N, 31)
    double*              __restrict__ ws,
    unsigned*            __restrict__ ctr,
    float*               __restrict__ out,
    int n)
{
    const int t   = threadIdx.x;
    const int i   = blockIdx.x * (256 / 4) + (t >> 2);
    const int sub = t & 3;

    float loss_w = 0.0f;
    float pm_f   = 0.0f;

    if (i < n) {
        // own 16 channels: one uint4 of fp8 -> 16 floats in registers
        float fA[16];
        {
            union { uint4 u; unsigned w[4]; } Au;
            Au.u = reinterpret_cast<const uint4*>(tab8 + (size_t)i * CH)[sub];
            #pragma unroll
            for (int q = 0; q < 4; ++q) {
                const f2 p0 = __builtin_amdgcn_cvt_pk_f32_fp8(Au.w[q], false);
                const f2 p1 = __builtin_amdgcn_cvt_pk_f32_fp8(Au.w[q], true);
                fA[4 * q + 0] = p0[0]; fA[4 * q + 1] = p0[1];
                fA[4 * q + 2] = p1[0]; fA[4 * q + 3] = p1[1];
            }
        }

        const int lab = labels[i];
        const int* nrow = nidx + (size_t)i * KNB;

        float m  = -1e30f;  // running max logit
        float se = 0.0f;
        float sp = 0.0f;
        int   cnt = 0;

        #pragma unroll 4
        for (int j = 0; j < KNB; ++j) {
            const int nj = nrow[j];                       // quad-broadcast

            union { uint4 u; unsigned w[4]; } Bu;
            Bu.u = reinterpret_cast<const uint4*>(tab8 + (size_t)nj * CH)[sub];

            float s = 0.0f;
            #pragma unroll
            for (int q = 0; q < 4; ++q) {
                const f2 p0 = __builtin_amdgcn_cvt_pk_f32_fp8(Bu.w[q], false);
                const f2 p1 = __builtin_amdgcn_cvt_pk_f32_fp8(Bu.w[q], true);
                float d;
                d = fA[4 * q + 0] - p0[0]; s = fmaf(d, d, s);
                d = fA[4 * q + 1] - p0[1]; s = fmaf(d, d, s);
                d = fA[4 * q + 2] - p1[0]; s = fmaf(d, d, s);
                d = fA[4 * q + 3] - p1[1]; s = fmaf(d, d, s);
            }
            s += __shfl_xor(s, 1);
            s += __shfl_xor(s, 2);

            const float l = -(sqrtf(s) + 1e-8f);
            const bool pm = (labels[nj] == lab);          // quad-broadcast
            cnt += pm ? 1 : 0;

            if (l > m) {
                const float r = __expf((m - l) * TEMP_INV);
                se *= r;
                sp *= r;
                m = l;
            }
            const float e = __expf((l - m) * TEMP_INV);
            se += e;
            if (pm) sp += e;
        }

        if (sub == 0 && cnt > 0 && cnt < KNB) {
            loss_w = -logf(sp / se + 1e-8f);
            pm_f   = 1.0f;
        }
    }

    __shared__ float s_l[256];
    __shared__ float s_c[256];
    s_l[t] = loss_w;
    s_c[t] = pm_f;
    __syncthreads();
    #pragma unroll
    for (int off = 128; off > 0; off >>= 1) {
        if (t < off) {
            s_l[t] += s_l[t + off];
            s_c[t] += s_c[t + off];
        }
        __syncthreads();
    }
    if (t == 0) {
        atomicAdd(ws,     (double)s_l[0]);
        atomicAdd(ws + 1, (double)s_c[0]);
        __threadfence();
        const unsigned old = atomicAdd(ctr, 1u);
        if (old == gridDim.x - 1) {
            const double sl = atomicAdd(ws, 0.0);
            const double sc = atomicAdd(ws + 1, 0.0);
            const double c  = (sc < 1.0) ? 1.0 : sc;
            out[0] = (float)(sl / c);   // WEIGHT = 1.0
        }
    }
}

// ---------------------------------------------------------------------------
// Fallback path (R2-exact, proven): fp16 table / f32 direct + separate finalize
// ---------------------------------------------------------------------------
__global__ __launch_bounds__(256) void ch_cvt(
    const float* __restrict__ in, __half* __restrict__ out, int total8)
{
    const int idx = blockIdx.x * blockDim.x + threadIdx.x;
    if (idx >= total8) return;
    const float4* ip = reinterpret_cast<const float4*>(in) + (size_t)idx * 2;
    const float4 a = ip[0];
    const float4 b = ip[1];
    union { uint4 u; __half2 h[4]; } o;
    o.h[0] = __floats2half2_rn(a.x, a.y);
    o.h[1] = __floats2half2_rn(a.z, a.w);
    o.h[2] = __floats2half2_rn(b.x, b.y);
    o.h[3] = __floats2half2_rn(b.z, b.w);
    reinterpret_cast<uint4*>(out)[idx] = o.u;
}

__device__ __forceinline__ float dot2acc(h2 d, float s) {
    return __builtin_amdgcn_fdot2(d, d, s, false);
}

template <bool FP16>
__global__ __launch_bounds__(256) void ch_main4(
    const float*  __restrict__ feat,
    const __half* __restrict__ tab,
    const int*    __restrict__ labels,
    const int*    __restrict__ nidx,
    double*       __restrict__ ws,
    int n)
{
    const int t   = threadIdx.x;
    const int i   = blockIdx.x * (256 / 4) + (t >> 2);
    const int sub = t & 3;

    float loss_w = 0.0f;
    float pm_f   = 0.0f;

    if (i < n) {
        float f[16];
        union { uint4 u[2]; h2 h[8]; } A;
        if constexpr (FP16) {
            const uint4* ap = reinterpret_cast<const uint4*>(tab + (size_t)i * CH + sub * 16);
            A.u[0] = ap[0];
            A.u[1] = ap[1];
        } else {
            const float4* ap = reinterpret_cast<const float4*>(feat + (size_t)i * CH + sub * 16);
            #pragma unroll
            for (int q = 0; q < 4; ++q) {
                const float4 v = ap[q];
                f[4 * q]     = v.x;
                f[4 * q + 1] = v.y;
                f[4 * q + 2] = v.z;
                f[4 * q + 3] = v.w;
            }
        }

        const int lab = labels[i];
        float m = -1e30f, se = 0.0f, sp = 0.0f;
        int cnt = 0;

        #pragma unroll 2
        for (int j = 0; j < KNB; ++j) {
            const int nj = nidx[(size_t)i * KNB + j];

            float s = 0.0f;
            if constexpr (FP16) {
                union { uint4 u[2]; h2 h[8]; } B;
                const uint4* bp = reinterpret_cast<const uint4*>(tab + (size_t)nj * CH + sub * 16);
                B.u[0] = bp[0];
                B.u[1] = bp[1];
                #pragma unroll
                for (int q = 0; q < 8; ++q) {
                    const h2 d = A.h[q] - B.h[q];
                    s = dot2acc(d, s);
                }
            } else {
                const float4* bp = reinterpret_cast<const float4*>(feat + (size_t)nj * CH + sub * 16);
                #pragma unroll
                for (int q = 0; q < 4; ++q) {
                    const float4 v = bp[q];
                    const float dx = f[4 * q]     - v.x;
                    const float dy = f[4 * q + 1] - v.y;
                    const float dz = f[4 * q + 2] - v.z;
                    const float dw = f[4 * q + 3] - v.w;
                    s += dx * dx + dy * dy + dz * dz + dw * dw;
                }
            }
            s += __shfl_xor(s, 1);
            s += __shfl_xor(s, 2);

            const float l = -(sqrtf(s) + 1e-8f);
            const bool pm = (labels[nj] == lab);
            cnt += pm ? 1 : 0;

            if (l > m) {
                const float r = __expf((m - l) * TEMP_INV);
                se *= r; sp *= r; m = l;
            }
            const float e = __expf((l - m) * TEMP_INV);
            se += e;
            if (pm) sp += e;
        }

        if (sub == 0 && cnt > 0 && cnt < KNB) {
            loss_w = -logf(sp / se + 1e-8f);
            pm_f   = 1.0f;
        }
    }

    __shared__ float s_l[256];
    __shared__ float s_c[256];
    s_l[t] = loss_w;
    s_c[t] = pm_f;
    __syncthreads();
    #pragma unroll
    for (int off = 128; off > 0; off >>= 1) {
        if (t < off) {
            s_l[t] += s_l[t + off];
            s_c[t] += s_c[t + off];
        }
        __syncthreads();
    }
    if (t == 0) {
        atomicAdd(ws,     (double)s_l[0]);
        atomicAdd(ws + 1, (double)s_c[0]);
    }
}

__global__ void ch_finalize(const double* __restrict__ ws, float* __restrict__ out) {
    double c = ws[1];
    if (c < 1.0) c = 1.0;
    out[0] = (float)(ws[0] / c);   // WEIGHT = 1.0
}

extern "C" void kernel_launch(void* const* d_in, const int* in_sizes, int n_in,
                              void* d_out, int out_size, void* d_ws, size_t ws_size,
                              hipStream_t stream) {
    const float* feat   = (const float*)d_in[0];
    const int*   labels = (const int*)d_in[1];
    const int*   nidx   = (const int*)d_in[2];
    float*       out    = (float*)d_out;
    double*      ws     = (double*)d_ws;
    unsigned*    ctr    = (unsigned*)((char*)d_ws + 16);

    const int n = in_sizes[1];                 // N = 100000
    const int total8 = n * CH / 8;

    if (ws_size >= 256 + (size_t)n * CH) {              // fp8 table: N*64 B
        unsigned char* tab = (unsigned char*)d_ws + 256;
        ch_cvt8<<<(total8 + 255) / 256, 256, 0, stream>>>(feat, tab, ws, ctr, total8);
        const int blocks = (n + 63) / 64;               // 64 points per block
        ch_main8q<<<blocks, 256, 0, stream>>>(tab, labels, nidx, ws, ctr, out, n);
        return;
    }

    ch_init_ws<<<1, 1, 0, stream>>>(ws, ctr);
    const int blocks = (n + 63) / 64;
    if (ws_size >= 256 + (size_t)n * CH * 2) {          // fp16 table
        __half* tab = reinterpret_cast<__half*>((char*)d_ws + 256);
        ch_cvt<<<(total8 + 255) / 256, 256, 0, stream>>>(feat, tab, total8);
        ch_main4<true><<<blocks, 256, 0, stream>>>(feat, tab, labels, nidx, ws, n);
    } else {                                            // f32 direct
        ch_main4<false><<<blocks, 256, 0, stream>>>(feat, nullptr, labels, nidx, ws, n);
    }
    ch_finalize<<<1, 1, 0, stream>>>(ws, out);
}

// Round 14
// 79.537 us; speedup vs baseline: 1.4069x; 1.3674x over previous
//
#include <hip/hip_runtime.h>
#include <hip/hip_fp16.h>

#define KNB 31
#define CH 64
#define TEMP_INV 10.0f   // 1 / temperature(0.1)

typedef _Float16 h2 __attribute__((ext_vector_type(2)));
typedef float f2 __attribute__((ext_vector_type(2)));

// ---------------------------------------------------------------------------
// ws layout:
//   bytes [0, 16)    : double ws[2]  (sum(loss*mask), sum(mask))
//   bytes [16, 20)   : unsigned ctr (unused in this 3-dispatch structure)
//   bytes [256, ...) : fp8 feature table (N*64 B) | fp16 table (N*128 B)
//
// NOTE (R13 lesson): NO __threadfence in the main kernel. A per-block
// device-scope fence (L2 writeback/inv) run 1563x destroys the L2 hit rate
// of the gather stream: +45% dur at identical FETCH_SIZE (L3 absorbs the
// extra misses, so HBM counters don't show it). Finalize stays a separate
// 1-thread kernel.
// ---------------------------------------------------------------------------

__global__ void ch_init_ws(double* __restrict__ ws, unsigned* __restrict__ ctr) {
    ws[0] = 0.0;
    ws[1] = 0.0;
    *ctr  = 0u;
}

// features f32 -> fp8 e4m3 table (8 floats -> 8 bytes per thread); zeroes ws.
__global__ __launch_bounds__(256) void ch_cvt8(
    const float* __restrict__ in, unsigned char* __restrict__ out,
    double* __restrict__ ws, int total8)
{
    const int idx = blockIdx.x * blockDim.x + threadIdx.x;
    if (idx == 0) { ws[0] = 0.0; ws[1] = 0.0; }
    if (idx >= total8) return;
    const float4* ip = reinterpret_cast<const float4*>(in) + (size_t)idx * 2;
    const float4 a = ip[0];
    const float4 b = ip[1];
    unsigned lo = 0u, hi = 0u;
    lo = __builtin_amdgcn_cvt_pk_fp8_f32(a.x, a.y, lo, false);
    lo = __builtin_amdgcn_cvt_pk_fp8_f32(a.z, a.w, lo, true);
    hi = __builtin_amdgcn_cvt_pk_fp8_f32(b.x, b.y, hi, false);
    hi = __builtin_amdgcn_cvt_pk_fp8_f32(b.z, b.w, hi, true);
    uint2 o; o.x = lo; o.y = hi;
    reinterpret_cast<uint2*>(out)[idx] = o;
}

// fp8 main — R8-exact (proven 69.5 us): 4 lanes/point, lane sub owns 16
// channels (one uint4 = 16 fp8), quad-cooperative 64 B row gathers, online
// softmax. No finalize tail, no fence.
__global__ __launch_bounds__(256) void ch_main8q(
    const unsigned char* __restrict__ tab8,   // (N, 64) fp8 e4m3
    const int*           __restrict__ labels, // (N,)
    const int*           __restrict__ nidx,   // (N, 31)
    double*              __restrict__ ws,
    int n)
{
    const int t   = threadIdx.x;
    const int i   = blockIdx.x * (256 / 4) + (t >> 2);
    const int sub = t & 3;

    float loss_w = 0.0f;
    float pm_f   = 0.0f;

    if (i < n) {
        // own 16 channels: one uint4 of fp8 -> 16 floats in registers
        float fA[16];
        {
            union { uint4 u; unsigned w[4]; } Au;
            Au.u = reinterpret_cast<const uint4*>(tab8 + (size_t)i * CH)[sub];
            #pragma unroll
            for (int q = 0; q < 4; ++q) {
                const f2 p0 = __builtin_amdgcn_cvt_pk_f32_fp8(Au.w[q], false);
                const f2 p1 = __builtin_amdgcn_cvt_pk_f32_fp8(Au.w[q], true);
                fA[4 * q + 0] = p0[0]; fA[4 * q + 1] = p0[1];
                fA[4 * q + 2] = p1[0]; fA[4 * q + 3] = p1[1];
            }
        }

        const int lab = labels[i];
        const int* nrow = nidx + (size_t)i * KNB;

        float m  = -1e30f;  // running max logit
        float se = 0.0f;
        float sp = 0.0f;
        int   cnt = 0;

        #pragma unroll 4
        for (int j = 0; j < KNB; ++j) {
            const int nj = nrow[j];                       // quad-broadcast

            union { uint4 u; unsigned w[4]; } Bu;
            Bu.u = reinterpret_cast<const uint4*>(tab8 + (size_t)nj * CH)[sub];

            float s = 0.0f;
            #pragma unroll
            for (int q = 0; q < 4; ++q) {
                const f2 p0 = __builtin_amdgcn_cvt_pk_f32_fp8(Bu.w[q], false);
                const f2 p1 = __builtin_amdgcn_cvt_pk_f32_fp8(Bu.w[q], true);
                float d;
                d = fA[4 * q + 0] - p0[0]; s = fmaf(d, d, s);
                d = fA[4 * q + 1] - p0[1]; s = fmaf(d, d, s);
                d = fA[4 * q + 2] - p1[0]; s = fmaf(d, d, s);
                d = fA[4 * q + 3] - p1[1]; s = fmaf(d, d, s);
            }
            s += __shfl_xor(s, 1);
            s += __shfl_xor(s, 2);

            const float l = -(sqrtf(s) + 1e-8f);
            const bool pm = (labels[nj] == lab);          // quad-broadcast
            cnt += pm ? 1 : 0;

            if (l > m) {
                const float r = __expf((m - l) * TEMP_INV);
                se *= r;
                sp *= r;
                m = l;
            }
            const float e = __expf((l - m) * TEMP_INV);
            se += e;
            if (pm) sp += e;
        }

        if (sub == 0 && cnt > 0 && cnt < KNB) {
            loss_w = -logf(sp / se + 1e-8f);
            pm_f   = 1.0f;
        }
    }

    __shared__ float s_l[256];
    __shared__ float s_c[256];
    s_l[t] = loss_w;
    s_c[t] = pm_f;
    __syncthreads();
    #pragma unroll
    for (int off = 128; off > 0; off >>= 1) {
        if (t < off) {
            s_l[t] += s_l[t + off];
            s_c[t] += s_c[t + off];
        }
        __syncthreads();
    }
    if (t == 0) {
        atomicAdd(ws,     (double)s_l[0]);
        atomicAdd(ws + 1, (double)s_c[0]);
    }
}

// ---------------------------------------------------------------------------
// Fallback path (R2-exact, proven): fp16 table / f32 direct
// ---------------------------------------------------------------------------
__global__ __launch_bounds__(256) void ch_cvt(
    const float* __restrict__ in, __half* __restrict__ out, int total8)
{
    const int idx = blockIdx.x * blockDim.x + threadIdx.x;
    if (idx >= total8) return;
    const float4* ip = reinterpret_cast<const float4*>(in) + (size_t)idx * 2;
    const float4 a = ip[0];
    const float4 b = ip[1];
    union { uint4 u; __half2 h[4]; } o;
    o.h[0] = __floats2half2_rn(a.x, a.y);
    o.h[1] = __floats2half2_rn(a.z, a.w);
    o.h[2] = __floats2half2_rn(b.x, b.y);
    o.h[3] = __floats2half2_rn(b.z, b.w);
    reinterpret_cast<uint4*>(out)[idx] = o.u;
}

__device__ __forceinline__ float dot2acc(h2 d, float s) {
    return __builtin_amdgcn_fdot2(d, d, s, false);
}

template <bool FP16>
__global__ __launch_bounds__(256) void ch_main4(
    const float*  __restrict__ feat,
    const __half* __restrict__ tab,
    const int*    __restrict__ labels,
    const int*    __restrict__ nidx,
    double*       __restrict__ ws,
    int n)
{
    const int t   = threadIdx.x;
    const int i   = blockIdx.x * (256 / 4) + (t >> 2);
    const int sub = t & 3;

    float loss_w = 0.0f;
    float pm_f   = 0.0f;

    if (i < n) {
        float f[16];
        union { uint4 u[2]; h2 h[8]; } A;
        if constexpr (FP16) {
            const uint4* ap = reinterpret_cast<const uint4*>(tab + (size_t)i * CH + sub * 16);
            A.u[0] = ap[0];
            A.u[1] = ap[1];
        } else {
            const float4* ap = reinterpret_cast<const float4*>(feat + (size_t)i * CH + sub * 16);
            #pragma unroll
            for (int q = 0; q < 4; ++q) {
                const float4 v = ap[q];
                f[4 * q]     = v.x;
                f[4 * q + 1] = v.y;
                f[4 * q + 2] = v.z;
                f[4 * q + 3] = v.w;
            }
        }

        const int lab = labels[i];
        float m = -1e30f, se = 0.0f, sp = 0.0f;
        int cnt = 0;

        #pragma unroll 2
        for (int j = 0; j < KNB; ++j) {
            const int nj = nidx[(size_t)i * KNB + j];

            float s = 0.0f;
            if constexpr (FP16) {
                union { uint4 u[2]; h2 h[8]; } B;
                const uint4* bp = reinterpret_cast<const uint4*>(tab + (size_t)nj * CH + sub * 16);
                B.u[0] = bp[0];
                B.u[1] = bp[1];
                #pragma unroll
                for (int q = 0; q < 8; ++q) {
                    const h2 d = A.h[q] - B.h[q];
                    s = dot2acc(d, s);
                }
            } else {
                const float4* bp = reinterpret_cast<const float4*>(feat + (size_t)nj * CH + sub * 16);
                #pragma unroll
                for (int q = 0; q < 4; ++q) {
                    const float4 v = bp[q];
                    const float dx = f[4 * q]     - v.x;
                    const float dy = f[4 * q + 1] - v.y;
                    const float dz = f[4 * q + 2] - v.z;
                    const float dw = f[4 * q + 3] - v.w;
                    s += dx * dx + dy * dy + dz * dz + dw * dw;
                }
            }
            s += __shfl_xor(s, 1);
            s += __shfl_xor(s, 2);

            const float l = -(sqrtf(s) + 1e-8f);
            const bool pm = (labels[nj] == lab);
            cnt += pm ? 1 : 0;

            if (l > m) {
                const float r = __expf((m - l) * TEMP_INV);
                se *= r; sp *= r; m = l;
            }
            const float e = __expf((l - m) * TEMP_INV);
            se += e;
            if (pm) sp += e;
        }

        if (sub == 0 && cnt > 0 && cnt < KNB) {
            loss_w = -logf(sp / se + 1e-8f);
            pm_f   = 1.0f;
        }
    }

    __shared__ float s_l[256];
    __shared__ float s_c[256];
    s_l[t] = loss_w;
    s_c[t] = pm_f;
    __syncthreads();
    #pragma unroll
    for (int off = 128; off > 0; off >>= 1) {
        if (t < off) {
            s_l[t] += s_l[t + off];
            s_c[t] += s_c[t + off];
        }
        __syncthreads();
    }
    if (t == 0) {
        atomicAdd(ws,     (double)s_l[0]);
        atomicAdd(ws + 1, (double)s_c[0]);
    }
}

__global__ void ch_finalize(const double* __restrict__ ws, float* __restrict__ out) {
    double c = ws[1];
    if (c < 1.0) c = 1.0;
    out[0] = (float)(ws[0] / c);   // WEIGHT = 1.0
}

extern "C" void kernel_launch(void* const* d_in, const int* in_sizes, int n_in,
                              void* d_out, int out_size, void* d_ws, size_t ws_size,
                              hipStream_t stream) {
    const float* feat   = (const float*)d_in[0];
    const int*   labels = (const int*)d_in[1];
    const int*   nidx   = (const int*)d_in[2];
    float*       out    = (float*)d_out;
    double*      ws     = (double*)d_ws;
    unsigned*    ctr    = (unsigned*)((char*)d_ws + 16);

    const int n = in_sizes[1];                 // N = 100000
    const int total8 = n * CH / 8;

    if (ws_size >= 256 + (size_t)n * CH) {              // fp8 table: N*64 B
        unsigned char* tab = (unsigned char*)d_ws + 256;
        ch_cvt8<<<(total8 + 255) / 256, 256, 0, stream>>>(feat, tab, ws, total8);
        const int blocks = (n + 63) / 64;               // 64 points per block
        ch_main8q<<<blocks, 256, 0, stream>>>(tab, labels, nidx, ws, n);
        ch_finalize<<<1, 1, 0, stream>>>(ws, out);
        return;
    }

    ch_init_ws<<<1, 1, 0, stream>>>(ws, ctr);
    const int blocks = (n + 63) / 64;
    if (ws_size >= 256 + (size_t)n * CH * 2) {          // fp16 table
        __half* tab = reinterpret_cast<__half*>((char*)d_ws + 256);
        ch_cvt<<<(total8 + 255) / 256, 256, 0, stream>>>(feat, tab, total8);
        ch_main4<true><<<blocks, 256, 0, stream>>>(feat, tab, labels, nidx, ws, n);
    } else {                                            // f32 direct
        ch_main4<false><<<blocks, 256, 0, stream>>>(feat, nullptr, labels, nidx, ws, n);
    }
    ch_finalize<<<1, 1, 0, stream>>>(ws, out);
}